// Round 8
// baseline (201.827 us; speedup 1.0000x reference)
//
#include <hip/hip_runtime.h>
#include <hip/hip_fp16.h>

#define NN 50000
#define BSHIFT 8
#define NBK ((NN + 255) >> 8)   // 196 buckets of 256 nodes
#define CHUNK 4096
#define CAP 8192

typedef __attribute__((ext_vector_type(8))) _Float16 f16x8;
typedef __attribute__((ext_vector_type(4))) float f32x4;

__device__ __forceinline__ float recw(unsigned r) {
    unsigned short us = (unsigned short)(r >> 16);
    __half h;
    __builtin_memcpy(&h, &us, 2);
    return __half2float(h);
}
__device__ __forceinline__ float2 h2f2(unsigned v) {
    __half2 h;
    __builtin_memcpy(&h, &v, 4);
    return __half22float2(h);
}
__device__ __forceinline__ unsigned f2h2(float a, float b) {
    __half2 h = __floats2half2_rn(a, b);
    unsigned u;
    __builtin_memcpy(&u, &h, 4);
    return u;
}
__device__ __forceinline__ f16x8 as_f16x8(uint4 v) {
    f16x8 r;
    __builtin_memcpy(&r, &v, 16);
    return r;
}
__device__ __forceinline__ unsigned short f2h1(float v) {
    __half h = __float2half(v);
    unsigned short us;
    __builtin_memcpy(&us, &h, 2);
    return us;
}

// ---------------- x -> fp16 convert ----------------

__global__ __launch_bounds__(256) void cvt_x(const float* __restrict__ x,
                                             unsigned* __restrict__ x16, int total4) {
    int i = blockIdx.x * 256 + threadIdx.x;
    if (i >= total4) return;
    float4 v = reinterpret_cast<const float4*>(x)[i];
    uint2 o;
    o.x = f2h2(v.x, v.y);
    o.y = f2h2(v.z, v.w);
    reinterpret_cast<uint2*>(x16)[i] = o;
}

// ---------------- W -> fp16 fragment-order pack (both layers) ----------------

__global__ __launch_bounds__(256) void prep_w(const float* __restrict__ W1s,
                                              const float* __restrict__ W1d,
                                              const float* __restrict__ W2s,
                                              const float* __restrict__ W2d,
                                              unsigned short* __restrict__ Bp) {
    int idx = blockIdx.x * 256 + threadIdx.x;
    if (idx >= 16384) return;
    int layer = idx >> 13;
    int rem = idx & 8191;
    int j = rem & 7;
    int l = (rem >> 3) & 63;
    int jt = (rem >> 9) & 3;
    int ks = rem >> 11;
    int k = ks * 32 + (l >> 4) * 8 + j;
    int col = jt * 16 + (l & 15);
    const float* Ws = layer ? W2s : W1s;
    const float* Wd = layer ? W2d : W1d;
    float v = (k < 64) ? Ws[k * 64 + col] : Wd[(k - 64) * 64 + col];
    Bp[idx] = f2h1(v);
}

// ---------------- pass A: per-bucket edge counts ----------------

__global__ __launch_bounds__(256) void bucket_count(const int* __restrict__ eiS, int Es,
                                                    const int* __restrict__ eiD, int Ed,
                                                    int* __restrict__ cntS,
                                                    int* __restrict__ cntD) {
    __shared__ int h[NBK];
    int rel = blockIdx.y;
    const int* dst = rel ? (eiD + Ed) : (eiS + Es);
    int E = rel ? Ed : Es;
    int* cnt = rel ? cntD : cntS;
    int base = blockIdx.x * CHUNK;
    if (base >= E) return;
    for (int i = threadIdx.x; i < NBK; i += 256) h[i] = 0;
    __syncthreads();
    int end = (base + CHUNK < E) ? base + CHUNK : E;
    for (int e = base + threadIdx.x; e < end; e += 256)
        atomicAdd(&h[dst[e] >> BSHIFT], 1);
    __syncthreads();
    for (int i = threadIdx.x; i < NBK; i += 256)
        if (h[i]) atomicAdd(&cnt[i], h[i]);
}

// ---------------- pass B: scan bucket counts ----------------

__global__ __launch_bounds__(256) void bucket_scan(const int* __restrict__ cntS,
                                                   const int* __restrict__ cntD,
                                                   int* __restrict__ baseS,
                                                   int* __restrict__ baseD,
                                                   int* __restrict__ curS,
                                                   int* __restrict__ curD,
                                                   int* __restrict__ offsS,
                                                   int* __restrict__ offsD) {
    __shared__ int sA[256], sB[256];
    const int* cnt = blockIdx.x ? cntD : cntS;
    int* base = blockIdx.x ? baseD : baseS;
    int* cur  = blockIdx.x ? curD : curS;
    int* offs = blockIdx.x ? offsD : offsS;
    int t = threadIdx.x;
    int v = (t < NBK) ? cnt[t] : 0;
    sA[t] = v;
    __syncthreads();
    int* pin = sA; int* pout = sB;
    for (int st = 1; st < 256; st <<= 1) {
        int x = pin[t];
        if (t >= st) x += pin[t - st];
        pout[t] = x;
        __syncthreads();
        int* tmp = pin; pin = pout; pout = tmp;
    }
    int incl = pin[t];
    int excl = incl - v;
    if (t < NBK) { base[t] = excl; cur[t] = excl; }
    if (t == NBK - 1) { base[NBK] = incl; offs[NN] = incl; }
}

// ---------------- pass C: scatter packed records ----------------

__global__ __launch_bounds__(256) void bucket_scatter(const int* __restrict__ eiS, int Es,
                                                      const int* __restrict__ eiD, int Ed,
                                                      int* __restrict__ curS,
                                                      int* __restrict__ curD,
                                                      unsigned* __restrict__ recS,
                                                      unsigned* __restrict__ recD) {
    __shared__ int h[NBK];
    __shared__ int rb[NBK];
    int rel = blockIdx.y;
    const int* ei = rel ? eiD : eiS;
    int E = rel ? Ed : Es;
    int* cur = rel ? curD : curS;
    unsigned* rec = rel ? recD : recS;
    int base = blockIdx.x * CHUNK;
    if (base >= E) return;
    const int* src = ei;
    const int* dst = ei + E;
    int end = (base + CHUNK < E) ? base + CHUNK : E;

    for (int i = threadIdx.x; i < NBK; i += 256) h[i] = 0;
    __syncthreads();
    for (int e = base + threadIdx.x; e < end; e += 256)
        atomicAdd(&h[dst[e] >> BSHIFT], 1);
    __syncthreads();
    for (int i = threadIdx.x; i < NBK; i += 256) {
        int c = h[i];
        rb[i] = c ? atomicAdd(&cur[i], c) : 0;
    }
    __syncthreads();
    for (int i = threadIdx.x; i < NBK; i += 256) h[i] = 0;
    __syncthreads();
    for (int e = base + threadIdx.x; e < end; e += 256) {
        int d = dst[e];
        int s = src[e];
        int b = d >> BSHIFT;
        int p = atomicAdd(&h[b], 1);
        rec[rb[b] + p] = (unsigned)s | ((unsigned)(d & 255) << 16);
    }
}

// ---------------- pass D: per-bucket finalize ----------------

__global__ __launch_bounds__(256) void bucket_finalize(const int* __restrict__ baseS,
                                                       const int* __restrict__ baseD,
                                                       unsigned* __restrict__ recS,
                                                       unsigned* __restrict__ recD,
                                                       int* __restrict__ offsS,
                                                       int* __restrict__ offsD,
                                                       float* __restrict__ dinvS,
                                                       float* __restrict__ dinvD) {
    __shared__ unsigned recs[CAP];
    __shared__ int lc[256], sA[256], sB[256];
    int rel = blockIdx.y;
    const int* base = rel ? baseD : baseS;
    unsigned* rec = rel ? recD : recS;
    int* offs = rel ? offsD : offsS;
    float* dinv = rel ? dinvD : dinvS;
    int b = blockIdx.x;
    int b0 = base[b], b1 = base[b + 1];
    int cnt = b1 - b0;
    int t = threadIdx.x;
    lc[t] = 0;
    __syncthreads();
    for (int i = t; i < cnt; i += 256) {
        unsigned r = rec[b0 + i];
        if (i < CAP) recs[i] = r;
        atomicAdd(&lc[r >> 16], 1);
    }
    __syncthreads();
    int v = lc[t];
    int g = (b << BSHIFT) + t;
    if (g < NN) dinv[g] = rsqrtf((float)v + 1.0f);
    sA[t] = v;
    __syncthreads();
    int* pin = sA; int* pout = sB;
    for (int st = 1; st < 256; st <<= 1) {
        int x = pin[t];
        if (t >= st) x += pin[t - st];
        pout[t] = x;
        __syncthreads();
        int* tmp = pin; pin = pout; pout = tmp;
    }
    int excl = pin[t] - v;
    if (g < NN) offs[g] = b0 + excl;
    lc[t] = excl;
    __syncthreads();
    for (int i = t; i < cnt; i += 256) {
        unsigned r = (i < CAP) ? recs[i] : rec[b0 + i];
        int p = atomicAdd(&lc[r >> 16], 1);
        rec[b0 + p] = r & 0xFFFFu;
    }
}

// ---------------- pack: rec = src | half(dinv[src])<<16 ----------------

__global__ __launch_bounds__(256) void pack_rec(unsigned* __restrict__ recS, int Es,
                                                unsigned* __restrict__ recD, int Ed,
                                                const float* __restrict__ dinvS,
                                                const float* __restrict__ dinvD) {
    int i = blockIdx.x * 256 + threadIdx.x;
    if (i < Es) {
        unsigned s = recS[i] & 0xFFFFu;
        recS[i] = s | ((unsigned)f2h1(dinvS[s]) << 16);
    }
    if (i < Ed) {
        unsigned s = recD[i] & 0xFFFFu;
        recD[i] = s | ((unsigned)f2h1(dinvD[s]) << 16);
    }
}

// ---------------- gather both relations -> fp16 A matrix [n,128] ----------------
// One wave per node. Bulk-load the node's entire adjacency (<=64 edges) into the
// wave's registers with ONE vector load, then broadcast per-pair via __shfl.
// Removes the rec-load -> feat-addr serial chain: all feat addresses are ready
// immediately, unroll-4 keeps 4+ feat loads in flight.

__global__ __launch_bounds__(256) void gather_agg(const int* __restrict__ offsS,
                                                  const unsigned* __restrict__ recS,
                                                  const int* __restrict__ offsD,
                                                  const unsigned* __restrict__ recD,
                                                  const unsigned* __restrict__ feat,
                                                  const float* __restrict__ dinvS,
                                                  const float* __restrict__ dinvD,
                                                  unsigned* __restrict__ A, int n) {
    int wid = (blockIdx.x * 256 + threadIdx.x) >> 6;
    int lane = threadIdx.x & 63;
    if (wid >= n) return;
    int grp = lane >> 5;
    int col = lane & 31;

    float dS = dinvS[wid];
    float dD = dinvD[wid];

    int eS0 = offsS[wid], eS1 = offsS[wid + 1];
    int eD0 = offsD[wid], eD1 = offsD[wid + 1];
    int nbS = eS1 - eS0;
    int nbD = eD1 - eD0;
    int cS = (nbS < 64) ? nbS : 64;
    int cD = (nbD < 64) ? nbD : 64;

    // bulk adjacency load: lane i holds rec[e0+i]; 0 => w=+0.0h (contributes 0)
    unsigned rvS = (lane < cS) ? recS[eS0 + lane] : 0u;
    unsigned rvD = (lane < cD) ? recD[eD0 + lane] : 0u;

    // self loop (group 0 only)
    float2 sf = h2f2(feat[wid * 32 + col]);
    float ws0 = grp ? 0.0f : dS;
    float wd0 = grp ? 0.0f : dD;
    float2 accS = make_float2(ws0 * sf.x, ws0 * sf.y);
    float2 accD = make_float2(wd0 * sf.x, wd0 * sf.y);

    int npS = (cS + 1) >> 1;  // pairs (grp0 = even edge, grp1 = odd edge)
    int npD = (cD + 1) >> 1;

#pragma unroll 4
    for (int i = 0; i < npS; i++) {
        unsigned r = __shfl(rvS, 2 * i + grp, 64);
        unsigned v = feat[(r & 0xFFFFu) * 32u + col];
        float w = recw(r);
        float2 f = h2f2(v);
        accS.x = fmaf(w, f.x, accS.x);
        accS.y = fmaf(w, f.y, accS.y);
    }
#pragma unroll 4
    for (int i = 0; i < npD; i++) {
        unsigned r = __shfl(rvD, 2 * i + grp, 64);
        unsigned v = feat[(r & 0xFFFFu) * 32u + col];
        float w = recw(r);
        float2 f = h2f2(v);
        accD.x = fmaf(w, f.x, accD.x);
        accD.y = fmaf(w, f.y, accD.y);
    }

    // rare tail: degree > 64 (pairwise, old style)
    for (int e = eS0 + 64; e < eS1; e += 2) {
        unsigned r = (e + grp < eS1) ? recS[e + grp] : 0u;
        unsigned v = feat[(r & 0xFFFFu) * 32u + col];
        float w = recw(r);
        float2 f = h2f2(v);
        accS.x = fmaf(w, f.x, accS.x);
        accS.y = fmaf(w, f.y, accS.y);
    }
    for (int e = eD0 + 64; e < eD1; e += 2) {
        unsigned r = (e + grp < eD1) ? recD[e + grp] : 0u;
        unsigned v = feat[(r & 0xFFFFu) * 32u + col];
        float w = recw(r);
        float2 f = h2f2(v);
        accD.x = fmaf(w, f.x, accD.x);
        accD.y = fmaf(w, f.y, accD.y);
    }

    accS.x += __shfl_xor(accS.x, 32, 64);
    accS.y += __shfl_xor(accS.y, 32, 64);
    accD.x += __shfl_xor(accD.x, 32, 64);
    accD.y += __shfl_xor(accD.y, 32, 64);
    if (grp == 0) {
        A[(size_t)wid * 64 + col]      = f2h2(dS * accS.x, dS * accS.y);
        A[(size_t)wid * 64 + 32 + col] = f2h2(dD * accD.x, dD * accD.y);
    }
}

// ---------------- apply via fp16 MFMA: [n,128] @ [128,64], bias+relu epilogue ----------------

#define STORE_JT(ACC, JT)                                                     \
    {                                                                         \
        int colj = (JT) * 16 + lr;                                            \
        float bs = ba[colj] + bb[colj];                                       \
        _Pragma("unroll")                                                     \
        for (int r = 0; r < 4; r++) {                                         \
            float v = fmaxf(ACC[r] + bs, 0.0f);                               \
            outH[(size_t)(m0 + lh * 4 + r) * 64 + colj] = f2h1(v);            \
        }                                                                     \
    }

#define HEAD_JT(ACC, JT)                                                      \
    {                                                                         \
        int colj = (JT) * 16 + lr;                                            \
        float bs = ba[colj] + bb[colj];                                       \
        float w0 = Wlin[colj * 3 + 0];                                        \
        float w1 = Wlin[colj * 3 + 1];                                        \
        float w2 = Wlin[colj * 3 + 2];                                        \
        _Pragma("unroll")                                                     \
        for (int r = 0; r < 4; r++) {                                         \
            float v = fmaxf(ACC[r] + bs, 0.0f);                               \
            h0[r] = fmaf(v, w0, h0[r]);                                       \
            h1[r] = fmaf(v, w1, h1[r]);                                       \
            h2[r] = fmaf(v, w2, h2[r]);                                       \
        }                                                                     \
    }

template <int HEAD>
__global__ __launch_bounds__(256) void apply_mfma(const unsigned* __restrict__ A,
                                                  const unsigned short* __restrict__ Bp,
                                                  const float* __restrict__ ba,
                                                  const float* __restrict__ bb,
                                                  const float* __restrict__ Wlin,
                                                  const float* __restrict__ blin,
                                                  unsigned short* __restrict__ outH,
                                                  float* __restrict__ out3, int n) {
    int wid = (blockIdx.x * 256 + threadIdx.x) >> 6;
    int l = threadIdx.x & 63;
    int m0 = wid * 16;
    if (m0 >= n) return;
    int lr = l & 15;
    int lh = l >> 4;

    const uint4* Bv = reinterpret_cast<const uint4*>(Bp);
    f32x4 acc0 = {0.f, 0.f, 0.f, 0.f};
    f32x4 acc1 = {0.f, 0.f, 0.f, 0.f};
    f32x4 acc2 = {0.f, 0.f, 0.f, 0.f};
    f32x4 acc3 = {0.f, 0.f, 0.f, 0.f};

#pragma unroll
    for (int ks = 0; ks < 4; ks++) {
        uint4 av = *reinterpret_cast<const uint4*>(A + (size_t)(m0 + lr) * 64 + ks * 16 + lh * 4);
        f16x8 af = as_f16x8(av);
        uint4 b0 = Bv[(ks * 4 + 0) * 64 + l];
        uint4 b1 = Bv[(ks * 4 + 1) * 64 + l];
        uint4 b2 = Bv[(ks * 4 + 2) * 64 + l];
        uint4 b3 = Bv[(ks * 4 + 3) * 64 + l];
        acc0 = __builtin_amdgcn_mfma_f32_16x16x32_f16(af, as_f16x8(b0), acc0, 0, 0, 0);
        acc1 = __builtin_amdgcn_mfma_f32_16x16x32_f16(af, as_f16x8(b1), acc1, 0, 0, 0);
        acc2 = __builtin_amdgcn_mfma_f32_16x16x32_f16(af, as_f16x8(b2), acc2, 0, 0, 0);
        acc3 = __builtin_amdgcn_mfma_f32_16x16x32_f16(af, as_f16x8(b3), acc3, 0, 0, 0);
    }

    if (HEAD == 0) {
        STORE_JT(acc0, 0)
        STORE_JT(acc1, 1)
        STORE_JT(acc2, 2)
        STORE_JT(acc3, 3)
    } else {
        float h0[4] = {0.f, 0.f, 0.f, 0.f};
        float h1[4] = {0.f, 0.f, 0.f, 0.f};
        float h2[4] = {0.f, 0.f, 0.f, 0.f};
        HEAD_JT(acc0, 0)
        HEAD_JT(acc1, 1)
        HEAD_JT(acc2, 2)
        HEAD_JT(acc3, 3)
#pragma unroll
        for (int st = 1; st < 16; st <<= 1) {
#pragma unroll
            for (int r = 0; r < 4; r++) {
                h0[r] += __shfl_xor(h0[r], st, 64);
                h1[r] += __shfl_xor(h1[r], st, 64);
                h2[r] += __shfl_xor(h2[r], st, 64);
            }
        }
        if (lr == 0) {
#pragma unroll
            for (int r = 0; r < 4; r++) {
                int row = m0 + lh * 4 + r;
                out3[row * 3 + 0] = h0[r] + blin[0];
                out3[row * 3 + 1] = h1[r] + blin[1];
                out3[row * 3 + 2] = h2[r] + blin[2];
            }
        }
    }
}

extern "C" void kernel_launch(void* const* d_in, const int* in_sizes, int n_in,
                              void* d_out, int out_size, void* d_ws, size_t ws_size,
                              hipStream_t stream) {
    const float* x    = (const float*)d_in[0];
    const int*   eis  = (const int*)d_in[1];
    const int*   eid  = (const int*)d_in[2];
    const float* W1s  = (const float*)d_in[3];
    const float* b1s  = (const float*)d_in[4];
    const float* W1d  = (const float*)d_in[5];
    const float* b1d  = (const float*)d_in[6];
    const float* W2s  = (const float*)d_in[7];
    const float* b2s  = (const float*)d_in[8];
    const float* W2d  = (const float*)d_in[9];
    const float* b2d  = (const float*)d_in[10];
    const float* Wlin = (const float*)d_in[11];
    const float* blin = (const float*)d_in[12];

    const int N  = NN;
    const int Es = in_sizes[1] / 2;
    const int Ed = in_sizes[2] / 2;
    int Emax = (Es > Ed) ? Es : Ed;

    // workspace layout (4B units; every offset multiple of 4 units -> 16B aligned)
    int*   cntS  = (int*)d_ws;                  // [196]
    int*   cntD  = cntS + NBK;                  // [196]
    int*   baseS = cntD + NBK;                  // [200]
    int*   baseD = baseS + (NBK + 4);           // [200]
    int*   curS  = baseD + (NBK + 4);           // [196]
    int*   curD  = curS + NBK;                  // [196]
    int*   offsS = curD + NBK;                  // [50004]
    int*   offsD = offsS + (N + 4);             // [50004]
    float* dinvS = (float*)(offsD + (N + 4));   // [50000]
    float* dinvD = dinvS + N;                   // [50000]
    unsigned* recS = (unsigned*)(dinvD + N);    // [Es]
    unsigned* recD = recS + Es;                 // [Ed]
    unsigned* x16  = recD + Ed;                 // [N*32] fp16 x features
    unsigned* h16u = x16 + (size_t)N * 32;      // [N*32] fp16 layer-1 output
    unsigned* Abuf = h16u + (size_t)N * 32;     // [N*64] fp16 A matrix (aggS|aggD)
    unsigned short* Bp = (unsigned short*)(Abuf + (size_t)N * 64);  // [16384] halves
    unsigned short* h16 = (unsigned short*)h16u;

    // ---- prep: feature convert, W pack, CSR build ----
    hipMemsetAsync(cntS, 0, (size_t)2 * NBK * sizeof(int), stream);
    cvt_x<<<(N * 16 + 255) / 256, 256, 0, stream>>>(x, x16, N * 16);
    prep_w<<<64, 256, 0, stream>>>(W1s, W1d, W2s, W2d, Bp);
    dim3 egrid((Emax + CHUNK - 1) / CHUNK, 2);
    bucket_count<<<egrid, 256, 0, stream>>>(eis, Es, eid, Ed, cntS, cntD);
    bucket_scan<<<2, 256, 0, stream>>>(cntS, cntD, baseS, baseD, curS, curD, offsS, offsD);
    bucket_scatter<<<egrid, 256, 0, stream>>>(eis, Es, eid, Ed, curS, curD, recS, recD);
    dim3 fgrid(NBK, 2);
    bucket_finalize<<<fgrid, 256, 0, stream>>>(baseS, baseD, recS, recD, offsS, offsD,
                                               dinvS, dinvD);
    pack_rec<<<(Emax + 255) / 256, 256, 0, stream>>>(recS, Es, recD, Ed, dinvS, dinvD);

    int gatherBlocks = (N * 64 + 255) / 256;
    int mtiles = (N + 15) / 16;                       // 3125 waves
    int applyBlocks = (mtiles * 64 + 255) / 256;      // 782 blocks

    // ---- layer 1 ----
    gather_agg<<<gatherBlocks, 256, 0, stream>>>(offsS, recS, offsD, recD, x16,
                                                 dinvS, dinvD, Abuf, N);
    apply_mfma<0><<<applyBlocks, 256, 0, stream>>>(Abuf, Bp, b1s, b1d,
                                                   nullptr, nullptr, h16, nullptr, N);

    // ---- layer 2 (head fused) ----
    gather_agg<<<gatherBlocks, 256, 0, stream>>>(offsS, recS, offsD, recD, h16u,
                                                 dinvS, dinvD, Abuf, N);
    apply_mfma<1><<<applyBlocks, 256, 0, stream>>>(Abuf, Bp + 8192, b2s, b2d,
                                                   Wlin, blin, nullptr, (float*)d_out, N);
}

// Round 9
// 176.893 us; speedup vs baseline: 1.1410x; 1.1410x over previous
//
#include <hip/hip_runtime.h>
#include <hip/hip_fp16.h>

#define NN 50000
#define BSHIFT 8
#define NBK ((NN + 255) >> 8)   // 196 buckets of 256 nodes
#define CHUNK 4096
#define CAP 8192

typedef __attribute__((ext_vector_type(8))) _Float16 f16x8;
typedef __attribute__((ext_vector_type(4))) float f32x4;

__device__ __forceinline__ float recw(unsigned r) {
    unsigned short us = (unsigned short)(r >> 16);
    __half h;
    __builtin_memcpy(&h, &us, 2);
    return __half2float(h);
}
__device__ __forceinline__ float2 h2f2(unsigned v) {
    __half2 h;
    __builtin_memcpy(&h, &v, 4);
    return __half22float2(h);
}
__device__ __forceinline__ unsigned f2h2(float a, float b) {
    __half2 h = __floats2half2_rn(a, b);
    unsigned u;
    __builtin_memcpy(&u, &h, 4);
    return u;
}
__device__ __forceinline__ f16x8 as_f16x8(uint4 v) {
    f16x8 r;
    __builtin_memcpy(&r, &v, 16);
    return r;
}
__device__ __forceinline__ unsigned short f2h1(float v) {
    __half h = __float2half(v);
    unsigned short us;
    __builtin_memcpy(&us, &h, 2);
    return us;
}

// ---------------- x -> fp16 convert ----------------

__global__ __launch_bounds__(256) void cvt_x(const float* __restrict__ x,
                                             unsigned* __restrict__ x16, int total4) {
    int i = blockIdx.x * 256 + threadIdx.x;
    if (i >= total4) return;
    float4 v = reinterpret_cast<const float4*>(x)[i];
    uint2 o;
    o.x = f2h2(v.x, v.y);
    o.y = f2h2(v.z, v.w);
    reinterpret_cast<uint2*>(x16)[i] = o;
}

// ---------------- W -> fp16 fragment-order pack (both layers) ----------------

__global__ __launch_bounds__(256) void prep_w(const float* __restrict__ W1s,
                                              const float* __restrict__ W1d,
                                              const float* __restrict__ W2s,
                                              const float* __restrict__ W2d,
                                              unsigned short* __restrict__ Bp) {
    int idx = blockIdx.x * 256 + threadIdx.x;
    if (idx >= 16384) return;
    int layer = idx >> 13;
    int rem = idx & 8191;
    int j = rem & 7;
    int l = (rem >> 3) & 63;
    int jt = (rem >> 9) & 3;
    int ks = rem >> 11;
    int k = ks * 32 + (l >> 4) * 8 + j;
    int col = jt * 16 + (l & 15);
    const float* Ws = layer ? W2s : W1s;
    const float* Wd = layer ? W2d : W1d;
    float v = (k < 64) ? Ws[k * 64 + col] : Wd[(k - 64) * 64 + col];
    Bp[idx] = f2h1(v);
}

// ---------------- pass A: per-bucket edge counts ----------------

__global__ __launch_bounds__(256) void bucket_count(const int* __restrict__ eiS, int Es,
                                                    const int* __restrict__ eiD, int Ed,
                                                    int* __restrict__ cntS,
                                                    int* __restrict__ cntD) {
    __shared__ int h[NBK];
    int rel = blockIdx.y;
    const int* dst = rel ? (eiD + Ed) : (eiS + Es);
    int E = rel ? Ed : Es;
    int* cnt = rel ? cntD : cntS;
    int base = blockIdx.x * CHUNK;
    if (base >= E) return;
    for (int i = threadIdx.x; i < NBK; i += 256) h[i] = 0;
    __syncthreads();
    int end = (base + CHUNK < E) ? base + CHUNK : E;
    for (int e = base + threadIdx.x; e < end; e += 256)
        atomicAdd(&h[dst[e] >> BSHIFT], 1);
    __syncthreads();
    for (int i = threadIdx.x; i < NBK; i += 256)
        if (h[i]) atomicAdd(&cnt[i], h[i]);
}

// ---------------- pass B: scan bucket counts ----------------

__global__ __launch_bounds__(256) void bucket_scan(const int* __restrict__ cntS,
                                                   const int* __restrict__ cntD,
                                                   int* __restrict__ baseS,
                                                   int* __restrict__ baseD,
                                                   int* __restrict__ curS,
                                                   int* __restrict__ curD,
                                                   int* __restrict__ offsS,
                                                   int* __restrict__ offsD) {
    __shared__ int sA[256], sB[256];
    const int* cnt = blockIdx.x ? cntD : cntS;
    int* base = blockIdx.x ? baseD : baseS;
    int* cur  = blockIdx.x ? curD : curS;
    int* offs = blockIdx.x ? offsD : offsS;
    int t = threadIdx.x;
    int v = (t < NBK) ? cnt[t] : 0;
    sA[t] = v;
    __syncthreads();
    int* pin = sA; int* pout = sB;
    for (int st = 1; st < 256; st <<= 1) {
        int x = pin[t];
        if (t >= st) x += pin[t - st];
        pout[t] = x;
        __syncthreads();
        int* tmp = pin; pin = pout; pout = tmp;
    }
    int incl = pin[t];
    int excl = incl - v;
    if (t < NBK) { base[t] = excl; cur[t] = excl; }
    if (t == NBK - 1) { base[NBK] = incl; offs[NN] = incl; }
}

// ---------------- pass C: scatter packed records ----------------

__global__ __launch_bounds__(256) void bucket_scatter(const int* __restrict__ eiS, int Es,
                                                      const int* __restrict__ eiD, int Ed,
                                                      int* __restrict__ curS,
                                                      int* __restrict__ curD,
                                                      unsigned* __restrict__ recS,
                                                      unsigned* __restrict__ recD) {
    __shared__ int h[NBK];
    __shared__ int rb[NBK];
    int rel = blockIdx.y;
    const int* ei = rel ? eiD : eiS;
    int E = rel ? Ed : Es;
    int* cur = rel ? curD : curS;
    unsigned* rec = rel ? recD : recS;
    int base = blockIdx.x * CHUNK;
    if (base >= E) return;
    const int* src = ei;
    const int* dst = ei + E;
    int end = (base + CHUNK < E) ? base + CHUNK : E;

    for (int i = threadIdx.x; i < NBK; i += 256) h[i] = 0;
    __syncthreads();
    for (int e = base + threadIdx.x; e < end; e += 256)
        atomicAdd(&h[dst[e] >> BSHIFT], 1);
    __syncthreads();
    for (int i = threadIdx.x; i < NBK; i += 256) {
        int c = h[i];
        rb[i] = c ? atomicAdd(&cur[i], c) : 0;
    }
    __syncthreads();
    for (int i = threadIdx.x; i < NBK; i += 256) h[i] = 0;
    __syncthreads();
    for (int e = base + threadIdx.x; e < end; e += 256) {
        int d = dst[e];
        int s = src[e];
        int b = d >> BSHIFT;
        int p = atomicAdd(&h[b], 1);
        rec[rb[b] + p] = (unsigned)s | ((unsigned)(d & 255) << 16);
    }
}

// ---------------- pass D: per-bucket finalize ----------------

__global__ __launch_bounds__(256) void bucket_finalize(const int* __restrict__ baseS,
                                                       const int* __restrict__ baseD,
                                                       unsigned* __restrict__ recS,
                                                       unsigned* __restrict__ recD,
                                                       int* __restrict__ offsS,
                                                       int* __restrict__ offsD,
                                                       float* __restrict__ dinvS,
                                                       float* __restrict__ dinvD) {
    __shared__ unsigned recs[CAP];
    __shared__ int lc[256], sA[256], sB[256];
    int rel = blockIdx.y;
    const int* base = rel ? baseD : baseS;
    unsigned* rec = rel ? recD : recS;
    int* offs = rel ? offsD : offsS;
    float* dinv = rel ? dinvD : dinvS;
    int b = blockIdx.x;
    int b0 = base[b], b1 = base[b + 1];
    int cnt = b1 - b0;
    int t = threadIdx.x;
    lc[t] = 0;
    __syncthreads();
    for (int i = t; i < cnt; i += 256) {
        unsigned r = rec[b0 + i];
        if (i < CAP) recs[i] = r;
        atomicAdd(&lc[r >> 16], 1);
    }
    __syncthreads();
    int v = lc[t];
    int g = (b << BSHIFT) + t;
    if (g < NN) dinv[g] = rsqrtf((float)v + 1.0f);
    sA[t] = v;
    __syncthreads();
    int* pin = sA; int* pout = sB;
    for (int st = 1; st < 256; st <<= 1) {
        int x = pin[t];
        if (t >= st) x += pin[t - st];
        pout[t] = x;
        __syncthreads();
        int* tmp = pin; pin = pout; pout = tmp;
    }
    int excl = pin[t] - v;
    if (g < NN) offs[g] = b0 + excl;
    lc[t] = excl;
    __syncthreads();
    for (int i = t; i < cnt; i += 256) {
        unsigned r = (i < CAP) ? recs[i] : rec[b0 + i];
        int p = atomicAdd(&lc[r >> 16], 1);
        rec[b0 + p] = r & 0xFFFFu;
    }
}

// ---------------- pack: rec = src | half(dinv[src])<<16 ----------------

__global__ __launch_bounds__(256) void pack_rec(unsigned* __restrict__ recS, int Es,
                                                unsigned* __restrict__ recD, int Ed,
                                                const float* __restrict__ dinvS,
                                                const float* __restrict__ dinvD) {
    int i = blockIdx.x * 256 + threadIdx.x;
    if (i < Es) {
        unsigned s = recS[i] & 0xFFFFu;
        recS[i] = s | ((unsigned)f2h1(dinvS[s]) << 16);
    }
    if (i < Ed) {
        unsigned s = recD[i] & 0xFFFFu;
        recD[i] = s | ((unsigned)f2h1(dinvD[s]) << 16);
    }
}

// ---------------- gather both relations -> fp16 A matrix [n,128] ----------------
// One wave per node; 16 lanes per feature row (uint2 = 4 features/lane), so one
// wave64 VMEM instruction fetches FOUR feature rows (4 edges). Each lane loads
// its own group's rec directly (no shfl in the chain). S/D batches interleaved,
// unroll-2 -> >=4 feat + 2 rec loads in flight. Group-reduce via shfl_xor(16,32).

__global__ __launch_bounds__(256) void gather_agg(const int* __restrict__ offsS,
                                                  const unsigned* __restrict__ recS,
                                                  const int* __restrict__ offsD,
                                                  const unsigned* __restrict__ recD,
                                                  const unsigned* __restrict__ feat,
                                                  const float* __restrict__ dinvS,
                                                  const float* __restrict__ dinvD,
                                                  unsigned* __restrict__ A, int n) {
    int wid = (blockIdx.x * 256 + threadIdx.x) >> 6;
    int lane = threadIdx.x & 63;
    if (wid >= n) return;
    int g = lane >> 4;        // edge slot within batch of 4
    int q = lane & 15;        // feature quad: features 4q..4q+3

    const uint2* featv = reinterpret_cast<const uint2*>(feat);  // row stride 16 uint2

    float dS = dinvS[wid];
    float dD = dinvD[wid];

    int eS0 = offsS[wid], eS1 = offsS[wid + 1];
    int eD0 = offsD[wid], eD1 = offsD[wid + 1];
    int nbS = (eS1 - eS0 + 3) >> 2;
    int nbD = (eD1 - eD0 + 3) >> 2;

    // self loop: only group 0 contributes
    uint2 sv = featv[(size_t)wid * 16 + q];
    float2 s0 = h2f2(sv.x), s1 = h2f2(sv.y);
    float wself = (g == 0) ? dS : 0.0f;
    float wselfD = (g == 0) ? dD : 0.0f;
    float aS0 = wself * s0.x, aS1 = wself * s0.y, aS2 = wself * s1.x, aS3 = wself * s1.y;
    float aD0 = wselfD * s0.x, aD1 = wselfD * s0.y, aD2 = wselfD * s1.x, aD3 = wselfD * s1.y;

#define BODY_S(I)                                                              \
    {                                                                          \
        int e = eS0 + 4 * (I) + g;                                             \
        unsigned r = (e < eS1) ? recS[e] : 0u;                                 \
        uint2 v = featv[(size_t)(r & 0xFFFFu) * 16 + q];                       \
        float w = recw(r);                                                     \
        float2 f0 = h2f2(v.x), f1 = h2f2(v.y);                                 \
        aS0 = fmaf(w, f0.x, aS0); aS1 = fmaf(w, f0.y, aS1);                    \
        aS2 = fmaf(w, f1.x, aS2); aS3 = fmaf(w, f1.y, aS3);                    \
    }
#define BODY_D(I)                                                              \
    {                                                                          \
        int e = eD0 + 4 * (I) + g;                                             \
        unsigned r = (e < eD1) ? recD[e] : 0u;                                 \
        uint2 v = featv[(size_t)(r & 0xFFFFu) * 16 + q];                       \
        float w = recw(r);                                                     \
        float2 f0 = h2f2(v.x), f1 = h2f2(v.y);                                 \
        aD0 = fmaf(w, f0.x, aD0); aD1 = fmaf(w, f0.y, aD1);                    \
        aD2 = fmaf(w, f1.x, aD2); aD3 = fmaf(w, f1.y, aD3);                    \
    }

    int nb = (nbS < nbD) ? nbS : nbD;
    int i = 0;
#pragma unroll 2
    for (; i < nb; i++) {
        BODY_S(i)
        BODY_D(i)
    }
#pragma unroll 2
    for (int is = i; is < nbS; is++) BODY_S(is)
#pragma unroll 2
    for (int id = i; id < nbD; id++) BODY_D(id)

#undef BODY_S
#undef BODY_D

    // reduce across the 4 groups (strides 16 and 32)
#pragma unroll
    for (int st = 16; st <= 32; st <<= 1) {
        aS0 += __shfl_xor(aS0, st, 64);
        aS1 += __shfl_xor(aS1, st, 64);
        aS2 += __shfl_xor(aS2, st, 64);
        aS3 += __shfl_xor(aS3, st, 64);
        aD0 += __shfl_xor(aD0, st, 64);
        aD1 += __shfl_xor(aD1, st, 64);
        aD2 += __shfl_xor(aD2, st, 64);
        aD3 += __shfl_xor(aD3, st, 64);
    }

    if (g == 0) {
        uint2 oS, oD;
        oS.x = f2h2(dS * aS0, dS * aS1);
        oS.y = f2h2(dS * aS2, dS * aS3);
        oD.x = f2h2(dD * aD0, dD * aD1);
        oD.y = f2h2(dD * aD2, dD * aD3);
        reinterpret_cast<uint2*>(A + (size_t)wid * 64)[q] = oS;
        reinterpret_cast<uint2*>(A + (size_t)wid * 64 + 32)[q] = oD;
    }
}

// ---------------- apply via fp16 MFMA: [n,128] @ [128,64], bias+relu epilogue ----------------

#define STORE_JT(ACC, JT)                                                     \
    {                                                                         \
        int colj = (JT) * 16 + lr;                                            \
        float bs = ba[colj] + bb[colj];                                       \
        _Pragma("unroll")                                                     \
        for (int r = 0; r < 4; r++) {                                         \
            float v = fmaxf(ACC[r] + bs, 0.0f);                               \
            outH[(size_t)(m0 + lh * 4 + r) * 64 + colj] = f2h1(v);            \
        }                                                                     \
    }

#define HEAD_JT(ACC, JT)                                                      \
    {                                                                         \
        int colj = (JT) * 16 + lr;                                            \
        float bs = ba[colj] + bb[colj];                                       \
        float w0 = Wlin[colj * 3 + 0];                                        \
        float w1 = Wlin[colj * 3 + 1];                                        \
        float w2 = Wlin[colj * 3 + 2];                                        \
        _Pragma("unroll")                                                     \
        for (int r = 0; r < 4; r++) {                                         \
            float v = fmaxf(ACC[r] + bs, 0.0f);                               \
            h0[r] = fmaf(v, w0, h0[r]);                                       \
            h1[r] = fmaf(v, w1, h1[r]);                                       \
            h2[r] = fmaf(v, w2, h2[r]);                                       \
        }                                                                     \
    }

template <int HEAD>
__global__ __launch_bounds__(256) void apply_mfma(const unsigned* __restrict__ A,
                                                  const unsigned short* __restrict__ Bp,
                                                  const float* __restrict__ ba,
                                                  const float* __restrict__ bb,
                                                  const float* __restrict__ Wlin,
                                                  const float* __restrict__ blin,
                                                  unsigned short* __restrict__ outH,
                                                  float* __restrict__ out3, int n) {
    int wid = (blockIdx.x * 256 + threadIdx.x) >> 6;
    int l = threadIdx.x & 63;
    int m0 = wid * 16;
    if (m0 >= n) return;
    int lr = l & 15;
    int lh = l >> 4;

    const uint4* Bv = reinterpret_cast<const uint4*>(Bp);
    f32x4 acc0 = {0.f, 0.f, 0.f, 0.f};
    f32x4 acc1 = {0.f, 0.f, 0.f, 0.f};
    f32x4 acc2 = {0.f, 0.f, 0.f, 0.f};
    f32x4 acc3 = {0.f, 0.f, 0.f, 0.f};

#pragma unroll
    for (int ks = 0; ks < 4; ks++) {
        uint4 av = *reinterpret_cast<const uint4*>(A + (size_t)(m0 + lr) * 64 + ks * 16 + lh * 4);
        f16x8 af = as_f16x8(av);
        uint4 b0 = Bv[(ks * 4 + 0) * 64 + l];
        uint4 b1 = Bv[(ks * 4 + 1) * 64 + l];
        uint4 b2 = Bv[(ks * 4 + 2) * 64 + l];
        uint4 b3 = Bv[(ks * 4 + 3) * 64 + l];
        acc0 = __builtin_amdgcn_mfma_f32_16x16x32_f16(af, as_f16x8(b0), acc0, 0, 0, 0);
        acc1 = __builtin_amdgcn_mfma_f32_16x16x32_f16(af, as_f16x8(b1), acc1, 0, 0, 0);
        acc2 = __builtin_amdgcn_mfma_f32_16x16x32_f16(af, as_f16x8(b2), acc2, 0, 0, 0);
        acc3 = __builtin_amdgcn_mfma_f32_16x16x32_f16(af, as_f16x8(b3), acc3, 0, 0, 0);
    }

    if (HEAD == 0) {
        STORE_JT(acc0, 0)
        STORE_JT(acc1, 1)
        STORE_JT(acc2, 2)
        STORE_JT(acc3, 3)
    } else {
        float h0[4] = {0.f, 0.f, 0.f, 0.f};
        float h1[4] = {0.f, 0.f, 0.f, 0.f};
        float h2[4] = {0.f, 0.f, 0.f, 0.f};
        HEAD_JT(acc0, 0)
        HEAD_JT(acc1, 1)
        HEAD_JT(acc2, 2)
        HEAD_JT(acc3, 3)
#pragma unroll
        for (int st = 1; st < 16; st <<= 1) {
#pragma unroll
            for (int r = 0; r < 4; r++) {
                h0[r] += __shfl_xor(h0[r], st, 64);
                h1[r] += __shfl_xor(h1[r], st, 64);
                h2[r] += __shfl_xor(h2[r], st, 64);
            }
        }
        if (lr == 0) {
#pragma unroll
            for (int r = 0; r < 4; r++) {
                int row = m0 + lh * 4 + r;
                out3[row * 3 + 0] = h0[r] + blin[0];
                out3[row * 3 + 1] = h1[r] + blin[1];
                out3[row * 3 + 2] = h2[r] + blin[2];
            }
        }
    }
}

extern "C" void kernel_launch(void* const* d_in, const int* in_sizes, int n_in,
                              void* d_out, int out_size, void* d_ws, size_t ws_size,
                              hipStream_t stream) {
    const float* x    = (const float*)d_in[0];
    const int*   eis  = (const int*)d_in[1];
    const int*   eid  = (const int*)d_in[2];
    const float* W1s  = (const float*)d_in[3];
    const float* b1s  = (const float*)d_in[4];
    const float* W1d  = (const float*)d_in[5];
    const float* b1d  = (const float*)d_in[6];
    const float* W2s  = (const float*)d_in[7];
    const float* b2s  = (const float*)d_in[8];
    const float* W2d  = (const float*)d_in[9];
    const float* b2d  = (const float*)d_in[10];
    const float* Wlin = (const float*)d_in[11];
    const float* blin = (const float*)d_in[12];

    const int N  = NN;
    const int Es = in_sizes[1] / 2;
    const int Ed = in_sizes[2] / 2;
    int Emax = (Es > Ed) ? Es : Ed;

    // workspace layout (4B units; every offset multiple of 4 units -> 16B aligned)
    int*   cntS  = (int*)d_ws;                  // [196]
    int*   cntD  = cntS + NBK;                  // [196]
    int*   baseS = cntD + NBK;                  // [200]
    int*   baseD = baseS + (NBK + 4);           // [200]
    int*   curS  = baseD + (NBK + 4);           // [196]
    int*   curD  = curS + NBK;                  // [196]
    int*   offsS = curD + NBK;                  // [50004]
    int*   offsD = offsS + (N + 4);             // [50004]
    float* dinvS = (float*)(offsD + (N + 4));   // [50000]
    float* dinvD = dinvS + N;                   // [50000]
    unsigned* recS = (unsigned*)(dinvD + N);    // [Es]
    unsigned* recD = recS + Es;                 // [Ed]
    unsigned* x16  = recD + Ed;                 // [N*32] fp16 x features
    unsigned* h16u = x16 + (size_t)N * 32;      // [N*32] fp16 layer-1 output
    unsigned* Abuf = h16u + (size_t)N * 32;     // [N*64] fp16 A matrix (aggS|aggD)
    unsigned short* Bp = (unsigned short*)(Abuf + (size_t)N * 64);  // [16384] halves
    unsigned short* h16 = (unsigned short*)h16u;

    // ---- prep: feature convert, W pack, CSR build ----
    hipMemsetAsync(cntS, 0, (size_t)2 * NBK * sizeof(int), stream);
    cvt_x<<<(N * 16 + 255) / 256, 256, 0, stream>>>(x, x16, N * 16);
    prep_w<<<64, 256, 0, stream>>>(W1s, W1d, W2s, W2d, Bp);
    dim3 egrid((Emax + CHUNK - 1) / CHUNK, 2);
    bucket_count<<<egrid, 256, 0, stream>>>(eis, Es, eid, Ed, cntS, cntD);
    bucket_scan<<<2, 256, 0, stream>>>(cntS, cntD, baseS, baseD, curS, curD, offsS, offsD);
    bucket_scatter<<<egrid, 256, 0, stream>>>(eis, Es, eid, Ed, curS, curD, recS, recD);
    dim3 fgrid(NBK, 2);
    bucket_finalize<<<fgrid, 256, 0, stream>>>(baseS, baseD, recS, recD, offsS, offsD,
                                               dinvS, dinvD);
    pack_rec<<<(Emax + 255) / 256, 256, 0, stream>>>(recS, Es, recD, Ed, dinvS, dinvD);

    int gatherBlocks = (N * 64 + 255) / 256;
    int mtiles = (N + 15) / 16;                       // 3125 waves
    int applyBlocks = (mtiles * 64 + 255) / 256;      // 782 blocks

    // ---- layer 1 ----
    gather_agg<<<gatherBlocks, 256, 0, stream>>>(offsS, recS, offsD, recD, x16,
                                                 dinvS, dinvD, Abuf, N);
    apply_mfma<0><<<applyBlocks, 256, 0, stream>>>(Abuf, Bp, b1s, b1d,
                                                   nullptr, nullptr, h16, nullptr, N);

    // ---- layer 2 (head fused) ----
    gather_agg<<<gatherBlocks, 256, 0, stream>>>(offsS, recS, offsD, recD, h16u,
                                                 dinvS, dinvD, Abuf, N);
    apply_mfma<1><<<applyBlocks, 256, 0, stream>>>(Abuf, Bp + 8192, b2s, b2d,
                                                   Wlin, blin, nullptr, (float*)d_out, N);
}